// Round 10
// baseline (27.215 us; speedup 1.0000x reference)
//
#include <hip/hip_runtime.h>

// Problem constants (fixed by reference setup_inputs): D=32 detectors,
// in_s = out_s = 64, row stride 2048 floats, B = 8192.
#define NDET    32
#define SEG     64
#define ROWLEN  2048
#define DGRP    4                  // detectors per block
#define XCOLS   (DGRP * SEG)       // 256 f32 = 1KB contiguous per row
#define TILE_R  64                 // rows per block
#define THREADS 256
#define XLSTR   264                // x LDS row stride (bf16)
#define WLSTR   72                 // W LDS o-row stride (bf16)
#define YLSTR   260                // y LDS row stride (f32)

typedef __bf16 bf16x8 __attribute__((ext_vector_type(8)));
typedef __bf16 bf16x4 __attribute__((ext_vector_type(4)));
typedef float  f32x4  __attribute__((ext_vector_type(4)));

__device__ __forceinline__ bf16x4 cvt4(f32x4 a) {
  bf16x4 r;
  r[0] = (__bf16)a[0]; r[1] = (__bf16)a[1]; r[2] = (__bf16)a[2]; r[3] = (__bf16)a[3];
  return r;
}

// y[b, d*64+o] = sum_i x[b, d*64+i] * W[d*64+o, d*64+i]
//
// v10 = v8 (4 detectors/block -> 1KB row windows) x v9 (LDS output
// transpose). EVERY HBM-touching instruction now moves one complete 1KB
// contiguous window:
//   x loads : 1 instr = 1 row x 1KB          (16 instrs)
//   y stores: 1 instr = 1 row x 1KB          (16 instrs)
//   W loads : 256B windows, L2-hot           (16 instrs)
// Wave w computes detector w for all 64 rows; accs land in an overlaid
// LDS y-tile; store pass reads it back row-contiguous.
__global__ __launch_bounds__(THREADS) void ensemble_linear_v10(
    const float* __restrict__ x, const float* __restrict__ W,
    float* __restrict__ y) {
  const int dg     = blockIdx.y;
  const int dbase0 = dg * XCOLS;          // x/y column base; W block base
  const int r0     = blockIdx.x * TILE_R;
  const int t      = threadIdx.x;
  const int lane   = t & 63;
  const int wid    = t >> 6;              // 0..3 (= detector within group)
  const int rq  = lane >> 4;              // W staging: o-row within quad
  const int c4  = lane & 15;              // W staging: 16B chunk
  const int m16 = lane & 15;              // fragment M/N index
  const int kg  = lane >> 4;              // fragment k-group

  // Phase A: xls [64][XLSTR] bf16 (33792B) + wls [256][WLSTR] bf16 (36864B)
  // Phase B: yls [64][YLSTR] f32 (66560B) overlaid on the same region.
  __shared__ __align__(16) unsigned char smem[TILE_R * XLSTR * 2 + DGRP * SEG * WLSTR * 2];
  __bf16* xls = (__bf16*)smem;
  __bf16* wls = (__bf16*)(smem + TILE_R * XLSTR * 2);
  float*  yls = (float*)smem;

  // ---- x loads: one full 1KB contiguous row window per instruction ----
  f32x4 xv[16];
#pragma unroll
  for (int p = 0; p < 16; ++p) {
    const int row = p * 4 + wid;
    xv[p] = *(const f32x4*)(x + (size_t)(r0 + row) * ROWLEN + dbase0 + lane * 4);
  }

  // ---- W loads (L2-hot): wave wid loads its detector's 64x64 block ----
  f32x4 wv[16];
#pragma unroll
  for (int p = 0; p < 16; ++p) {
    const int o = p * 4 + rq;
    wv[p] = *(const f32x4*)(W + (size_t)(dbase0 + wid * SEG + o) * ROWLEN
                              + dbase0 + wid * SEG + c4 * 4);
  }

  // ---- stage to LDS (bf16) ----
#pragma unroll
  for (int p = 0; p < 16; ++p) {
    const int row = p * 4 + wid;
    *(bf16x4*)(&xls[row * XLSTR + lane * 4]) = cvt4(xv[p]);
  }
#pragma unroll
  for (int p = 0; p < 16; ++p) {
    const int o = p * 4 + rq;
    *(bf16x4*)(&wls[(wid * SEG + o) * WLSTR + c4 * 4]) = cvt4(wv[p]);
  }

  __syncthreads();   // barrier 1: tiles staged

  // ---- fragment reads into registers (wave wid: detector wid, 64 rows) ----
  bf16x8 wfrag[4][2];   // [o-group][kh]
#pragma unroll
  for (int g = 0; g < 4; ++g)
#pragma unroll
    for (int kh = 0; kh < 2; ++kh)
      wfrag[g][kh] = *(const bf16x8*)(
          &wls[(wid * SEG + g * 16 + m16) * WLSTR + kh * 32 + kg * 8]);

  bf16x8 afrag[4][2];   // [row-subtile][kh]
#pragma unroll
  for (int s = 0; s < 4; ++s) {
#pragma unroll
    for (int kh = 0; kh < 2; ++kh)
      afrag[s][kh] = *(const bf16x8*)(
          &xls[(s * 16 + m16) * XLSTR + wid * SEG + kh * 32 + kg * 8]);
  }

  __syncthreads();   // barrier 2: all reads done -> safe to overlay yls

  // ---- MFMA -> LDS y-tile. Swapped-operand (r3-verified): D = W . x^T.
  // acc(s,g): y row = s*16 + m16, col (in-detector) = g*16 + kg*4 .. +3.
#pragma unroll
  for (int s = 0; s < 4; ++s) {
#pragma unroll
    for (int g = 0; g < 4; ++g) {
      f32x4 acc = (f32x4){0.f, 0.f, 0.f, 0.f};
      acc = __builtin_amdgcn_mfma_f32_16x16x32_bf16(wfrag[g][0], afrag[s][0], acc, 0, 0, 0);
      acc = __builtin_amdgcn_mfma_f32_16x16x32_bf16(wfrag[g][1], afrag[s][1], acc, 0, 0, 0);
      *(f32x4*)(&yls[(s * 16 + m16) * YLSTR + wid * SEG + g * 16 + kg * 4]) = acc;
    }
  }

  __syncthreads();   // barrier 3: y-tile complete (rows span all waves)

  // ---- y store: one instruction = one full 1KB contiguous row ----
#pragma unroll
  for (int p = 0; p < 16; ++p) {
    const int row = p * 4 + wid;
    f32x4 v = *(const f32x4*)(&yls[row * YLSTR + lane * 4]);
    *(f32x4*)(y + (size_t)(r0 + row) * ROWLEN + dbase0 + lane * 4) = v;
  }
}

extern "C" void kernel_launch(void* const* d_in, const int* in_sizes, int n_in,
                              void* d_out, int out_size, void* d_ws, size_t ws_size,
                              hipStream_t stream) {
  const float* x = (const float*)d_in[0];
  const float* W = (const float*)d_in[1];
  float* y = (float*)d_out;
  const int B = in_sizes[0] / ROWLEN;   // 8192
  dim3 grid(B / TILE_R, NDET / DGRP);
  ensemble_linear_v10<<<grid, dim3(THREADS), 0, stream>>>(x, W, y);
}